// Round 1
// baseline (3131.249 us; speedup 1.0000x reference)
//
#include <hip/hip_runtime.h>
#include <math.h>

// ---------------------------------------------------------------------------
// Problem constants (bench is fixed-shape: b=1, T=2048, D=2048)
// ---------------------------------------------------------------------------
#define T_SEQ 2048
#define D_MODEL 2048
#define HEAD_DIM 64
#define N_HEADS 32
#define N_KV 8

// ---------------------------------------------------------------------------
// RoPE tables: llama3 scaled rope. cos/sin stored [t][i], i in [0,32)
// ---------------------------------------------------------------------------
__global__ void rope_tables_kernel(float* __restrict__ cosT, float* __restrict__ sinT,
                                   const int* __restrict__ start_pos, int T) {
    int t = blockIdx.x;
    int i = threadIdx.x;  // 0..31
    float pos = (float)(start_pos[0] + t);
    float expo = (float)i / 32.0f;                  // (2i)/64
    float inv_freq = 1.0f / powf(500000.0f, expo);
    const float two_pi = 6.283185307179586f;
    float wavelen = two_pi / inv_freq;
    const float low_wl = 8192.0f;    // orig_ctx / low_freq_factor
    const float high_wl = 2048.0f;   // orig_ctx / high_freq_factor
    float inv;
    if (wavelen > low_wl) {
        inv = inv_freq / 32.0f;      // factor
    } else if (wavelen < high_wl) {
        inv = inv_freq;
    } else {
        float smooth = (8192.0f / wavelen - 1.0f) / 3.0f;  // (high-low)=3
        inv = (1.0f - smooth) * (inv_freq / 32.0f) + smooth * inv_freq;
    }
    float ang = pos * inv;
    cosT[t * 32 + i] = cosf(ang);
    sinT[t * 32 + i] = sinf(ang);
}

// ---------------------------------------------------------------------------
// GEMM: Y[t][o] = sum_d X[t][d] * W[o][d]   (A row-major, B^T row-major)
// 64x64 tile, BK=16, 256 threads, 4x4 acc per thread.
// headSplit: store Y at [(o/64)][t][o%64] (head-major) else [t][O].
// ---------------------------------------------------------------------------
__global__ __launch_bounds__(256) void gemm_nt_kernel(
    const float* __restrict__ X, const float* __restrict__ W, float* __restrict__ Y,
    int D, int O, int T, int headSplit) {
    __shared__ float As[16][68];  // [k][m], padded row stride 68 keeps float4 align
    __shared__ float Bs[16][68];
    int tid = threadIdx.x;
    int t0 = blockIdx.x * 64;
    int o0 = blockIdx.y * 64;
    int ry = tid >> 4, rx = tid & 15;
    float acc[4][4] = {};
    int lm = tid >> 2;          // 0..63 row within tile
    int lk = (tid & 3) * 4;     // 0,4,8,12 col within k-tile
    const float* xp = X + (size_t)(t0 + lm) * D + lk;
    const float* wp = W + (size_t)(o0 + lm) * D + lk;
    for (int k0 = 0; k0 < D; k0 += 16) {
        float4 xa = *(const float4*)(xp + k0);
        float4 wa = *(const float4*)(wp + k0);
        As[lk + 0][lm] = xa.x; As[lk + 1][lm] = xa.y;
        As[lk + 2][lm] = xa.z; As[lk + 3][lm] = xa.w;
        Bs[lk + 0][lm] = wa.x; Bs[lk + 1][lm] = wa.y;
        Bs[lk + 2][lm] = wa.z; Bs[lk + 3][lm] = wa.w;
        __syncthreads();
#pragma unroll
        for (int kk = 0; kk < 16; ++kk) {
            float a[4], b[4];
#pragma unroll
            for (int i = 0; i < 4; ++i) a[i] = As[kk][ry * 4 + i];
#pragma unroll
            for (int j = 0; j < 4; ++j) b[j] = Bs[kk][rx * 4 + j];
#pragma unroll
            for (int i = 0; i < 4; ++i)
#pragma unroll
                for (int j = 0; j < 4; ++j)
                    acc[i][j] = fmaf(a[i], b[j], acc[i][j]);
        }
        __syncthreads();
    }
#pragma unroll
    for (int i = 0; i < 4; ++i) {
        int t = t0 + ry * 4 + i;
#pragma unroll
        for (int j = 0; j < 4; ++j) {
            int o = o0 + rx * 4 + j;
            if (headSplit)
                Y[(size_t)(o >> 6) * ((size_t)T * 64) + (size_t)t * 64 + (o & 63)] = acc[i][j];
            else
                Y[(size_t)t * O + o] = acc[i][j];
        }
    }
}

// ---------------------------------------------------------------------------
// RoPE apply in-place on head-major buffer [h][t][64].
// One thread per (row, i<32) pair: x1=buf[i], x2=buf[i+32].
// ---------------------------------------------------------------------------
__global__ void rope_apply_kernel(float* __restrict__ buf, const float* __restrict__ cosT,
                                  const float* __restrict__ sinT, int T) {
    int gid = blockIdx.x * blockDim.x + threadIdx.x;
    int i = gid & 31;
    int row = gid >> 5;         // h*T + t
    int t = row & (T - 1);      // T is power of two
    float* p = buf + (size_t)row * 64;
    float c = cosT[t * 32 + i], s = sinT[t * 32 + i];
    float x1 = p[i], x2 = p[i + 32];
    p[i] = x1 * c - x2 * s;
    p[i + 32] = x2 * c + x1 * s;
}

// ---------------------------------------------------------------------------
// Attention: one block = 256 q rows of one head. K/V tiles in LDS.
// Each thread owns one q row: q[64] + acc[64] in registers.
// No max-subtraction: scores bounded well below exp overflow (|s| <~ 10).
// GQA: q head h uses kv head h/4.
// ---------------------------------------------------------------------------
__global__ __launch_bounds__(256) void attn_kernel(
    const float* __restrict__ Q, const float* __restrict__ K, const float* __restrict__ V,
    float* __restrict__ ctx, int T) {
    __shared__ float Ks[64][64];
    __shared__ float Vs[64][64];
    int h = blockIdx.y;
    int r0 = blockIdx.x * 256;
    int tid = threadIdx.x;
    int r = r0 + tid;

    const float* qrow = Q + ((size_t)h * T + r) * 64;
    float q[64];
#pragma unroll
    for (int d4 = 0; d4 < 16; ++d4) {
        float4 tq = *(const float4*)(qrow + d4 * 4);
        q[d4 * 4 + 0] = tq.x; q[d4 * 4 + 1] = tq.y;
        q[d4 * 4 + 2] = tq.z; q[d4 * 4 + 3] = tq.w;
    }
    float acc[64];
#pragma unroll
    for (int d = 0; d < 64; ++d) acc[d] = 0.0f;
    float l = 0.0f;
    const float scale = 0.125f;  // 1/sqrt(64)

    int hk = h >> 2;
    const float* Kb = K + (size_t)hk * T * 64;
    const float* Vb = V + (size_t)hk * T * 64;

    int ntiles = (r0 + 256) / 64;  // causal: keys up to r0+255
    for (int kt = 0; kt < ntiles; ++kt) {
        int k0 = kt * 64;
        __syncthreads();
#pragma unroll
        for (int it = 0; it < 4; ++it) {
            int idx = tid + 256 * it;     // float4 index 0..1023
            int row = idx >> 4, c4 = idx & 15;
            *(float4*)&Ks[row][c4 * 4] = *(const float4*)&Kb[(size_t)(k0 + row) * 64 + c4 * 4];
            *(float4*)&Vs[row][c4 * 4] = *(const float4*)&Vb[(size_t)(k0 + row) * 64 + c4 * 4];
        }
        __syncthreads();
#pragma unroll 2
        for (int j = 0; j < 64; ++j) {
            int jk = k0 + j;
            // dot(q, K[j]) with 4 partial chains for ILP
            float s0 = 0.f, s1 = 0.f, s2 = 0.f, s3 = 0.f;
#pragma unroll
            for (int d4 = 0; d4 < 16; ++d4) {
                s0 = fmaf(q[d4 * 4 + 0], Ks[j][d4 * 4 + 0], s0);
                s1 = fmaf(q[d4 * 4 + 1], Ks[j][d4 * 4 + 1], s1);
                s2 = fmaf(q[d4 * 4 + 2], Ks[j][d4 * 4 + 2], s2);
                s3 = fmaf(q[d4 * 4 + 3], Ks[j][d4 * 4 + 3], s3);
            }
            float s = (s0 + s1) + (s2 + s3);
            float p = (jk <= r) ? __expf(s * scale) : 0.0f;
            l += p;
#pragma unroll
            for (int d = 0; d < 64; ++d)
                acc[d] = fmaf(p, Vs[j][d], acc[d]);
        }
    }
    float inv = 1.0f / l;
    float* crow = ctx + (size_t)r * (N_HEADS * 64) + h * 64;
#pragma unroll
    for (int d4 = 0; d4 < 16; ++d4) {
        float4 tv;
        tv.x = acc[d4 * 4 + 0] * inv; tv.y = acc[d4 * 4 + 1] * inv;
        tv.z = acc[d4 * 4 + 2] * inv; tv.w = acc[d4 * 4 + 3] * inv;
        *(float4*)(crow + d4 * 4) = tv;
    }
}

// ---------------------------------------------------------------------------
extern "C" void kernel_launch(void* const* d_in, const int* in_sizes, int n_in,
                              void* d_out, int out_size, void* d_ws, size_t ws_size,
                              hipStream_t stream) {
    const float* x  = (const float*)d_in[0];
    const float* Wq = (const float*)d_in[1];
    const float* Wk = (const float*)d_in[2];
    const float* Wv = (const float*)d_in[3];
    const float* Wo = (const float*)d_in[4];
    const int* start_pos = (const int*)d_in[5];
    float* out = (float*)d_out;

    const int T = T_SEQ, D = D_MODEL;

    float* ws   = (float*)d_ws;
    float* cosT = ws;
    float* sinT = cosT + (size_t)T * 32;
    float* q    = sinT + (size_t)T * 32;                       // 32*T*64
    float* k    = q    + (size_t)N_HEADS * T * HEAD_DIM;       // 8*T*64
    float* v    = k    + (size_t)N_KV * T * HEAD_DIM;          // 8*T*64
    float* ctx  = v    + (size_t)N_KV * T * HEAD_DIM;          // T*2048

    rope_tables_kernel<<<dim3(T), dim3(32), 0, stream>>>(cosT, sinT, start_pos, T);

    gemm_nt_kernel<<<dim3(T / 64, D_MODEL / 64), dim3(256), 0, stream>>>(x, Wq, q, D, D_MODEL, T, 1);
    gemm_nt_kernel<<<dim3(T / 64, (N_KV * HEAD_DIM) / 64), dim3(256), 0, stream>>>(x, Wk, k, D, N_KV * HEAD_DIM, T, 1);
    gemm_nt_kernel<<<dim3(T / 64, (N_KV * HEAD_DIM) / 64), dim3(256), 0, stream>>>(x, Wv, v, D, N_KV * HEAD_DIM, T, 1);

    rope_apply_kernel<<<dim3((N_HEADS * T * 32) / 256), dim3(256), 0, stream>>>(q, cosT, sinT, T);
    rope_apply_kernel<<<dim3((N_KV * T * 32) / 256), dim3(256), 0, stream>>>(k, cosT, sinT, T);

    attn_kernel<<<dim3(T / 256, N_HEADS), dim3(256), 0, stream>>>(q, k, v, ctx, T);

    gemm_nt_kernel<<<dim3(T / 64, D_MODEL / 64), dim3(256), 0, stream>>>(ctx, Wo, out, D, D_MODEL, T, 0);
}

// Round 2
// 393.566 us; speedup vs baseline: 7.9561x; 7.9561x over previous
//
#include <hip/hip_runtime.h>
#include <math.h>

#define T_SEQ 2048
#define D_MODEL 2048
#define HEAD_DIM 64
#define N_HEADS 32
#define N_KV 8

using short8 = __attribute__((ext_vector_type(8))) short;
using f32x4  = __attribute__((ext_vector_type(4))) float;

#define MFMA16(a, b, c) __builtin_amdgcn_mfma_f32_16x16x32_bf16(a, b, c, 0, 0, 0)

__device__ __forceinline__ unsigned short f2bf(float f) {
    unsigned int u = __builtin_bit_cast(unsigned int, f);
    u += 0x7fff + ((u >> 16) & 1);   // round-to-nearest-even
    return (unsigned short)(u >> 16);
}
__device__ __forceinline__ float bf2f(unsigned short h) {
    unsigned int u = ((unsigned int)h) << 16;
    return __builtin_bit_cast(float, u);
}
__device__ __forceinline__ void gld_lds16(const ushort* g, ushort* l) {
    __builtin_amdgcn_global_load_lds((const __attribute__((address_space(1))) void*)g,
                                     (__attribute__((address_space(3))) void*)l, 16, 0, 0);
}

// ---------------------------------------------------------------------------
// RoPE tables (llama3 scaling), fp32. cos/sin [t][i], i in [0,32)
// ---------------------------------------------------------------------------
__global__ void rope_tables_kernel(float* __restrict__ cosT, float* __restrict__ sinT,
                                   const int* __restrict__ start_pos, int T) {
    int t = blockIdx.x;
    int i = threadIdx.x;  // 0..31
    float pos = (float)(start_pos[0] + t);
    float expo = (float)i / 32.0f;
    float inv_freq = 1.0f / powf(500000.0f, expo);
    const float two_pi = 6.283185307179586f;
    float wavelen = two_pi / inv_freq;
    const float low_wl = 8192.0f;
    const float high_wl = 2048.0f;
    float inv;
    if (wavelen > low_wl) {
        inv = inv_freq / 32.0f;
    } else if (wavelen < high_wl) {
        inv = inv_freq;
    } else {
        float smooth = (8192.0f / wavelen - 1.0f) / 3.0f;
        inv = (1.0f - smooth) * (inv_freq / 32.0f) + smooth * inv_freq;
    }
    float ang = pos * inv;
    cosT[t * 32 + i] = cosf(ang);
    sinT[t * 32 + i] = sinf(ang);
}

// ---------------------------------------------------------------------------
// fp32 -> bf16 cast, float4/ushort4 vectorized
// ---------------------------------------------------------------------------
__global__ __launch_bounds__(256) void cast_bf16_kernel(const float* __restrict__ in,
                                                        ushort* __restrict__ out, int n4) {
    int i = blockIdx.x * blockDim.x + threadIdx.x;
    if (i < n4) {
        float4 v = ((const float4*)in)[i];
        ushort4 o;
        o.x = f2bf(v.x); o.y = f2bf(v.y); o.z = f2bf(v.z); o.w = f2bf(v.w);
        ((ushort4*)out)[i] = o;
    }
}

// ---------------------------------------------------------------------------
// RoPE apply in-place on bf16 head-major buffer [h][t][64]
// ---------------------------------------------------------------------------
__global__ __launch_bounds__(256) void rope_apply_bf16(ushort* __restrict__ buf,
                                                       const float* __restrict__ cosT,
                                                       const float* __restrict__ sinT, int T) {
    int gid = blockIdx.x * blockDim.x + threadIdx.x;
    int i = gid & 31;
    int row = gid >> 5;           // h*T + t
    int t = row & (T - 1);
    ushort* p = buf + (size_t)row * 64;
    float c = cosT[t * 32 + i], s = sinT[t * 32 + i];
    float x1 = bf2f(p[i]), x2 = bf2f(p[i + 32]);
    p[i]      = f2bf(x1 * c - x2 * s);
    p[i + 32] = f2bf(x2 * c + x1 * s);
}

// ---------------------------------------------------------------------------
// MFMA GEMM: C[m][n] = sum_k A[m][k] * B[n][k]   (both bf16, K-contiguous)
// 128x128 tile, BK=32, 256 threads (4 waves, 2x2), 4x4 16x16x32 MFMAs/wave.
// MODE 0: C fp32 [M][N].  MODE 1: C bf16 head-major [n>>6][m][n&63].
// MODE 2: C bf16 transposed [N][M].
// ---------------------------------------------------------------------------
template <int MODE>
__global__ __launch_bounds__(256) void gemm_bt(const ushort* __restrict__ A,
                                               const ushort* __restrict__ B,
                                               void* __restrict__ Cout,
                                               int M, int N, int K) {
    __shared__ __align__(16) ushort As[128 * 32];
    __shared__ __align__(16) ushort Bs[128 * 32];
    const int tid = threadIdx.x;
    const int w = tid >> 6, l = tid & 63;
    const int m0 = blockIdx.x * 128, n0 = blockIdx.y * 128;
    const int wm = (w >> 1) * 64, wn = (w & 1) * 64;
    const int lr = l & 15;
    const int lk = (l >> 4) * 8;

    f32x4 zero = {0.f, 0.f, 0.f, 0.f};
    f32x4 acc[4][4];
#pragma unroll
    for (int i = 0; i < 4; ++i)
#pragma unroll
        for (int j = 0; j < 4; ++j) acc[i][j] = zero;

    // staging: per wave 2 instrs per operand; lds ushort base = si*512
    const int si0 = w * 2, si1 = w * 2 + 1;
    const int srow0 = si0 * 16 + (l >> 2);
    const int srow1 = si1 * 16 + (l >> 2);
    const int scol = (l & 3) * 8;
    const ushort* Ag0 = A + (size_t)(m0 + srow0) * K + scol;
    const ushort* Ag1 = A + (size_t)(m0 + srow1) * K + scol;
    const ushort* Bg0 = B + (size_t)(n0 + srow0) * K + scol;
    const ushort* Bg1 = B + (size_t)(n0 + srow1) * K + scol;
    ushort* Al0 = &As[si0 * 512]; ushort* Al1 = &As[si1 * 512];
    ushort* Bl0 = &Bs[si0 * 512]; ushort* Bl1 = &Bs[si1 * 512];

    for (int k0 = 0; k0 < K; k0 += 32) {
        gld_lds16(Ag0 + k0, Al0);
        gld_lds16(Ag1 + k0, Al1);
        gld_lds16(Bg0 + k0, Bl0);
        gld_lds16(Bg1 + k0, Bl1);
        __syncthreads();
        short8 af[4], bf[4];
#pragma unroll
        for (int i = 0; i < 4; ++i) af[i] = *(const short8*)&As[(wm + i * 16 + lr) * 32 + lk];
#pragma unroll
        for (int j = 0; j < 4; ++j) bf[j] = *(const short8*)&Bs[(wn + j * 16 + lr) * 32 + lk];
#pragma unroll
        for (int i = 0; i < 4; ++i)
#pragma unroll
            for (int j = 0; j < 4; ++j)
                acc[i][j] = MFMA16(af[i], bf[j], acc[i][j]);
        __syncthreads();
    }

    const int mbase = m0 + wm + (l >> 4) * 4;   // + i*16 + r
    const int nbase = n0 + wn + lr;             // + j*16
    if (MODE == 0) {
        float* C = (float*)Cout;
#pragma unroll
        for (int i = 0; i < 4; ++i)
#pragma unroll
            for (int j = 0; j < 4; ++j)
#pragma unroll
                for (int r = 0; r < 4; ++r)
                    C[(size_t)(mbase + i * 16 + r) * N + (nbase + j * 16)] = acc[i][j][r];
    } else if (MODE == 1) {
        ushort* C = (ushort*)Cout;
#pragma unroll
        for (int i = 0; i < 4; ++i)
#pragma unroll
            for (int j = 0; j < 4; ++j) {
                int n = nbase + j * 16;
                size_t base = (size_t)(n >> 6) * ((size_t)M * 64) + (size_t)(n & 63);
#pragma unroll
                for (int r = 0; r < 4; ++r)
                    C[base + (size_t)(mbase + i * 16 + r) * 64] = f2bf(acc[i][j][r]);
            }
    } else {
        ushort* C = (ushort*)Cout;  // [N][M]
#pragma unroll
        for (int i = 0; i < 4; ++i)
#pragma unroll
            for (int j = 0; j < 4; ++j) {
                int n = nbase + j * 16;
                int m = mbase + i * 16;
                ushort4 o;
                o.x = f2bf(acc[i][j][0]); o.y = f2bf(acc[i][j][1]);
                o.z = f2bf(acc[i][j][2]); o.w = f2bf(acc[i][j][3]);
                *(ushort4*)&C[(size_t)n * M + m] = o;
            }
    }
}

// ---------------------------------------------------------------------------
// Flash attention, MFMA bf16. One block = 64 q-rows of one head; 4 waves of
// 16 q-rows each. K [hk][t][64], Vt [hk][64][T] (pre-transposed), exact
// softmax without max-shift (|s*scale| <~ 5). GQA: kv head = h>>2.
// ---------------------------------------------------------------------------
__global__ __launch_bounds__(256) void attn_mfma(const ushort* __restrict__ Q,
                                                 const ushort* __restrict__ K,
                                                 const ushort* __restrict__ Vt,
                                                 ushort* __restrict__ ctx, int T) {
    __shared__ __align__(16) ushort Ks[64 * 64];       // [key][d]
    __shared__ __align__(16) ushort Vs[64 * 64];       // [d][key]
    __shared__ __align__(16) ushort Ps[4][16 * 64];    // per-wave [qrow][key]
    const int tid = threadIdx.x, w = tid >> 6, l = tid & 63;
    const int h = blockIdx.y, qt = blockIdx.x;
    const int hk = h >> 2;
    const int lr = l & 15;
    const int lk = (l >> 4) * 8;
    const int quad = l >> 4;
    const ushort* Kb = K + (size_t)hk * T * 64;
    const ushort* Vb = Vt + (size_t)hk * 64 * T;

    // Q fragments (A-operand layout), kept in regs for whole kernel
    const ushort* qp = Q + ((size_t)h * T + (size_t)qt * 64 + w * 16 + lr) * 64 + lk;
    short8 qf0 = *(const short8*)qp;
    short8 qf1 = *(const short8*)(qp + 32);

    f32x4 zero = {0.f, 0.f, 0.f, 0.f};
    f32x4 oacc[4];
#pragma unroll
    for (int j = 0; j < 4; ++j) oacc[j] = zero;
    float lsum[4] = {0.f, 0.f, 0.f, 0.f};

    // staging indices (8 KB per buffer, 2 wave-instrs per buffer per wave)
    const int si0 = w * 2, si1 = w * 2 + 1;
    const int srow0 = si0 * 8 + (l >> 3);
    const int srow1 = si1 * 8 + (l >> 3);
    const int scol = (l & 7) * 8;
    ushort* Kl0 = &Ks[si0 * 512]; ushort* Kl1 = &Ks[si1 * 512];
    ushort* Vl0 = &Vs[si0 * 512]; ushort* Vl1 = &Vs[si1 * 512];

    const int ntiles = qt + 1;
    const int qabs = qt * 64 + w * 16 + quad * 4;   // + r

    for (int kt = 0; kt < ntiles; ++kt) {
        const int k0 = kt * 64;
        gld_lds16(Kb + (size_t)(k0 + srow0) * 64 + scol, Kl0);
        gld_lds16(Kb + (size_t)(k0 + srow1) * 64 + scol, Kl1);
        gld_lds16(Vb + (size_t)srow0 * T + k0 + scol, Vl0);
        gld_lds16(Vb + (size_t)srow1 * T + k0 + scol, Vl1);
        __syncthreads();
        // S = Q @ K^T  (4 key-chunks of 16)
        f32x4 s[4];
#pragma unroll
        for (int j = 0; j < 4; ++j) {
            short8 kf0 = *(const short8*)&Ks[(j * 16 + lr) * 64 + lk];
            short8 kf1 = *(const short8*)&Ks[(j * 16 + lr) * 64 + 32 + lk];
            f32x4 z = zero;
            z = MFMA16(qf0, kf0, z);
            z = MFMA16(qf1, kf1, z);
            s[j] = z;
        }
        // mask + exp + stage P to per-wave LDS (C/D layout -> [qrow][key])
#pragma unroll
        for (int j = 0; j < 4; ++j) {
            int key = k0 + j * 16 + lr;
#pragma unroll
            for (int r = 0; r < 4; ++r) {
                float p = (key <= qabs + r) ? __expf(s[j][r] * 0.125f) : 0.f;
                lsum[r] += p;
                Ps[w][(quad * 4 + r) * 64 + j * 16 + lr] = f2bf(p);
            }
        }
        // O += P @ V  (read P back in A-operand layout; same-wave LDS dep)
#pragma unroll
        for (int ss = 0; ss < 2; ++ss) {
            short8 pf = *(const short8*)&Ps[w][lr * 64 + ss * 32 + lk];
#pragma unroll
            for (int j = 0; j < 4; ++j) {
                short8 vf = *(const short8*)&Vs[(j * 16 + lr) * 64 + ss * 32 + lk];
                oacc[j] = MFMA16(pf, vf, oacc[j]);
            }
        }
        __syncthreads();
    }
    // row-sum across the 16 lanes of each quad
#pragma unroll
    for (int r = 0; r < 4; ++r) {
        float v = lsum[r];
        v += __shfl_xor(v, 1); v += __shfl_xor(v, 2);
        v += __shfl_xor(v, 4); v += __shfl_xor(v, 8);
        lsum[r] = 1.f / v;
    }
    // write ctx [t][2048] bf16
#pragma unroll
    for (int j = 0; j < 4; ++j) {
        int col = h * 64 + j * 16 + lr;
#pragma unroll
        for (int r = 0; r < 4; ++r) {
            int row = qt * 64 + w * 16 + quad * 4 + r;
            ctx[(size_t)row * 2048 + col] = f2bf(oacc[j][r] * lsum[r]);
        }
    }
}

// ---------------------------------------------------------------------------
extern "C" void kernel_launch(void* const* d_in, const int* in_sizes, int n_in,
                              void* d_out, int out_size, void* d_ws, size_t ws_size,
                              hipStream_t stream) {
    const float* x  = (const float*)d_in[0];
    const float* Wq = (const float*)d_in[1];
    const float* Wk = (const float*)d_in[2];
    const float* Wv = (const float*)d_in[3];
    const float* Wo = (const float*)d_in[4];
    const int* start_pos = (const int*)d_in[5];
    float* out = (float*)d_out;

    const int T = T_SEQ, D = D_MODEL;
    const int KV = N_KV * HEAD_DIM;  // 512

    char* w = (char*)d_ws;
    float* cosT = (float*)w;            w += (size_t)T * 32 * 4;
    float* sinT = (float*)w;            w += (size_t)T * 32 * 4;
    ushort* xbf  = (ushort*)w;          w += (size_t)T * D * 2;     // 8 MB (aliased: ctx)
    ushort* wqbf = (ushort*)w;          w += (size_t)D * D * 2;     // 8 MB
    ushort* wkbf = (ushort*)w;          w += (size_t)KV * D * 2;    // 2 MB
    ushort* wvbf = (ushort*)w;          w += (size_t)KV * D * 2;    // 2 MB
    ushort* wobf = (ushort*)w;          w += (size_t)D * D * 2;     // 8 MB
    ushort* qbf  = (ushort*)w;          w += (size_t)N_HEADS * T * 64 * 2;  // 8 MB
    ushort* kbf  = (ushort*)w;          w += (size_t)N_KV * T * 64 * 2;     // 2 MB
    ushort* vtbf = (ushort*)w;          w += (size_t)N_KV * 64 * T * 2;     // 2 MB
    ushort* ctxbf = xbf;  // alias: x consumed by QKV GEMMs before attn writes ctx

    rope_tables_kernel<<<dim3(T), dim3(32), 0, stream>>>(cosT, sinT, start_pos, T);

    cast_bf16_kernel<<<dim3((T * D / 4) / 256), dim3(256), 0, stream>>>(x, xbf, T * D / 4);
    cast_bf16_kernel<<<dim3((D * D / 4) / 256), dim3(256), 0, stream>>>(Wq, wqbf, D * D / 4);
    cast_bf16_kernel<<<dim3((KV * D / 4) / 256), dim3(256), 0, stream>>>(Wk, wkbf, KV * D / 4);
    cast_bf16_kernel<<<dim3((KV * D / 4) / 256), dim3(256), 0, stream>>>(Wv, wvbf, KV * D / 4);
    cast_bf16_kernel<<<dim3((D * D / 4) / 256), dim3(256), 0, stream>>>(Wo, wobf, D * D / 4);

    gemm_bt<1><<<dim3(T / 128, D / 128), dim3(256), 0, stream>>>(xbf, wqbf, qbf, T, D, D);
    gemm_bt<1><<<dim3(T / 128, KV / 128), dim3(256), 0, stream>>>(xbf, wkbf, kbf, T, KV, D);
    gemm_bt<2><<<dim3(T / 128, KV / 128), dim3(256), 0, stream>>>(xbf, wvbf, vtbf, T, KV, D);

    rope_apply_bf16<<<dim3((N_HEADS * T * 32) / 256), dim3(256), 0, stream>>>(qbf, cosT, sinT, T);
    rope_apply_bf16<<<dim3((N_KV * T * 32) / 256), dim3(256), 0, stream>>>(kbf, cosT, sinT, T);

    attn_mfma<<<dim3(T / 64, N_HEADS), dim3(256), 0, stream>>>(qbf, kbf, vtbf, ctxbf, T);

    gemm_bt<0><<<dim3(T / 128, D / 128), dim3(256), 0, stream>>>(ctxbf, wobf, out, T, D, D);
}

// Round 3
// 257.210 us; speedup vs baseline: 12.1739x; 1.5301x over previous
//
#include <hip/hip_runtime.h>
#include <math.h>

#define T_SEQ 2048
#define D_MODEL 2048
#define HEAD_DIM 64
#define N_HEADS 32
#define N_KV 8

using short8 = __attribute__((ext_vector_type(8))) short;
using f32x4  = __attribute__((ext_vector_type(4))) float;

#define MFMA16(a, b, c) __builtin_amdgcn_mfma_f32_16x16x32_bf16(a, b, c, 0, 0, 0)

__device__ __forceinline__ unsigned short f2bf(float f) {
    unsigned int u = __builtin_bit_cast(unsigned int, f);
    u += 0x7fff + ((u >> 16) & 1);
    return (unsigned short)(u >> 16);
}
__device__ __forceinline__ float bf2f(unsigned short h) {
    unsigned int u = ((unsigned int)h) << 16;
    return __builtin_bit_cast(float, u);
}
__device__ __forceinline__ void gld_lds16(const ushort* g, ushort* l) {
    __builtin_amdgcn_global_load_lds((const __attribute__((address_space(1))) void*)g,
                                     (__attribute__((address_space(3))) void*)l, 16, 0, 0);
}

// ---------------------------------------------------------------------------
// RoPE tables (llama3 scaling), fp32, TRANSPOSED layout [i][T] so the GEMM
// epilogue can float4-load along t.
// ---------------------------------------------------------------------------
__global__ void rope_tables_kernel(float* __restrict__ cosT, float* __restrict__ sinT,
                                   const int* __restrict__ start_pos, int T) {
    int t = blockIdx.x;
    int i = threadIdx.x;  // 0..31
    float pos = (float)(start_pos[0] + t);
    float expo = (float)i / 32.0f;
    float inv_freq = 1.0f / powf(500000.0f, expo);
    const float two_pi = 6.283185307179586f;
    float wavelen = two_pi / inv_freq;
    const float low_wl = 8192.0f;
    const float high_wl = 2048.0f;
    float inv;
    if (wavelen > low_wl) {
        inv = inv_freq / 32.0f;
    } else if (wavelen < high_wl) {
        inv = inv_freq;
    } else {
        float smooth = (8192.0f / wavelen - 1.0f) / 3.0f;
        inv = (1.0f - smooth) * (inv_freq / 32.0f) + smooth * inv_freq;
    }
    float ang = pos * inv;
    cosT[i * T + t] = cosf(ang);
    sinT[i * T + t] = sinf(ang);
}

// ---------------------------------------------------------------------------
// One cast kernel for all five fp32->bf16 conversions (float4 granules).
// Segment sizes in float4: x 1048576, Wq 1048576, Wk 262144, Wv 262144, Wo 1048576
// ---------------------------------------------------------------------------
__global__ __launch_bounds__(256) void cast_all_kernel(
    const float* __restrict__ x, const float* __restrict__ wq,
    const float* __restrict__ wk, const float* __restrict__ wv,
    const float* __restrict__ wo,
    ushort* __restrict__ xb, ushort* __restrict__ wqb,
    ushort* __restrict__ wkb, ushort* __restrict__ wvb, ushort* __restrict__ wob) {
    int i = blockIdx.x * 256 + threadIdx.x;
    const float* src; ushort* dst; int off;
    if (i < 1048576)      { src = x;  dst = xb;  off = i; }
    else if (i < 2097152) { src = wq; dst = wqb; off = i - 1048576; }
    else if (i < 2359296) { src = wk; dst = wkb; off = i - 2097152; }
    else if (i < 2621440) { src = wv; dst = wvb; off = i - 2359296; }
    else                  { src = wo; dst = wob; off = i - 2621440; }
    float4 v = ((const float4*)src)[off];
    ushort4 o;
    o.x = f2bf(v.x); o.y = f2bf(v.y); o.z = f2bf(v.z); o.w = f2bf(v.w);
    ((ushort4*)dst)[off] = o;
}

// ---------------------------------------------------------------------------
// Fused QKV GEMM with RoPE epilogue for Q and K.
// C[m][n] = sum_k X[m][k]*W[n][k]; 128x128 tile, BK=32, 4 waves 2x2.
// grid.y: 0..15 -> Q (rope, head-major), 16..19 -> K (rope, head-major),
//         20..23 -> V (transposed [512][T], no rope).
// ---------------------------------------------------------------------------
__global__ __launch_bounds__(256) void gemm_qkv(
    const ushort* __restrict__ X, const ushort* __restrict__ Wqb,
    const ushort* __restrict__ Wkb, const ushort* __restrict__ Wvb,
    ushort* __restrict__ Qo, ushort* __restrict__ Ko, ushort* __restrict__ Vto,
    const float* __restrict__ cosT, const float* __restrict__ sinT,
    int T, int D) {
    __shared__ __align__(16) ushort As[128 * 32];
    __shared__ __align__(16) ushort Bs[128 * 32];
    const int tid = threadIdx.x;
    const int w = tid >> 6, l = tid & 63;
    const int m0 = blockIdx.x * 128;
    const int n0g = blockIdx.y * 128;

    const ushort* B;
    ushort* Cout;
    int n0;          // col offset within the selected weight matrix
    int doRope;
    if (n0g < 2048)      { B = Wqb + (size_t)n0g * D;          Cout = Qo;  n0 = n0g;        doRope = 1; }
    else if (n0g < 2560) { B = Wkb + (size_t)(n0g - 2048) * D; Cout = Ko;  n0 = n0g - 2048; doRope = 1; }
    else                 { B = Wvb + (size_t)(n0g - 2560) * D; Cout = Vto; n0 = n0g - 2560; doRope = 0; }

    const int wm = (w >> 1) * 64, wn = (w & 1) * 64;
    const int lr = l & 15;
    const int lk = (l >> 4) * 8;
    const int quad = l >> 4;

    f32x4 zero = {0.f, 0.f, 0.f, 0.f};
    f32x4 acc[4][4];
#pragma unroll
    for (int i = 0; i < 4; ++i)
#pragma unroll
        for (int j = 0; j < 4; ++j) acc[i][j] = zero;

    const int si0 = w * 2, si1 = w * 2 + 1;
    const int srow0 = si0 * 16 + (l >> 2);
    const int srow1 = si1 * 16 + (l >> 2);
    const int scol = (l & 3) * 8;
    const ushort* Ag0 = X + (size_t)(m0 + srow0) * D + scol;
    const ushort* Ag1 = X + (size_t)(m0 + srow1) * D + scol;
    const ushort* Bg0 = B + (size_t)srow0 * D + scol;
    const ushort* Bg1 = B + (size_t)srow1 * D + scol;
    ushort* Al0 = &As[si0 * 512]; ushort* Al1 = &As[si1 * 512];
    ushort* Bl0 = &Bs[si0 * 512]; ushort* Bl1 = &Bs[si1 * 512];

    for (int k0 = 0; k0 < D; k0 += 32) {
        gld_lds16(Ag0 + k0, Al0);
        gld_lds16(Ag1 + k0, Al1);
        gld_lds16(Bg0 + k0, Bl0);
        gld_lds16(Bg1 + k0, Bl1);
        __syncthreads();
        short8 af[4], bf[4];
#pragma unroll
        for (int i = 0; i < 4; ++i) af[i] = *(const short8*)&As[(wm + i * 16 + lr) * 32 + lk];
#pragma unroll
        for (int j = 0; j < 4; ++j) bf[j] = *(const short8*)&Bs[(wn + j * 16 + lr) * 32 + lk];
#pragma unroll
        for (int i = 0; i < 4; ++i)
#pragma unroll
            for (int j = 0; j < 4; ++j)
                acc[i][j] = MFMA16(af[i], bf[j], acc[i][j]);
        __syncthreads();
    }

    const int mbase = m0 + wm + quad * 4;   // + i*16, rows mbase..mbase+3 per acc reg
    if (doRope) {
        // head-major out [n>>6][t][n&63]; wave spans one 64-dim head block.
        // acc[i][j] (j=0,1) holds dim i1 = lr + j*16; acc[i][j+2] holds i1+32.
#pragma unroll
        for (int i = 0; i < 4; ++i) {
            int trow = mbase + i * 16;   // multiple of 4
#pragma unroll
            for (int j = 0; j < 2; ++j) {
                int i1 = lr + j * 16;
                float4 c4 = *(const float4*)&cosT[(size_t)i1 * T + trow];
                float4 s4 = *(const float4*)&sinT[(size_t)i1 * T + trow];
                int n1 = n0 + wn + lr + j * 16;
                int n2 = n1 + 32;
                size_t b1 = (size_t)(n1 >> 6) * ((size_t)T * 64) + (size_t)(n1 & 63);
                size_t b2 = (size_t)(n2 >> 6) * ((size_t)T * 64) + (size_t)(n2 & 63);
                float cs[4] = {c4.x, c4.y, c4.z, c4.w};
                float sn[4] = {s4.x, s4.y, s4.z, s4.w};
#pragma unroll
                for (int r = 0; r < 4; ++r) {
                    float x1 = acc[i][j][r], x2 = acc[i][j + 2][r];
                    Cout[b1 + (size_t)(trow + r) * 64] = f2bf(x1 * cs[r] - x2 * sn[r]);
                    Cout[b2 + (size_t)(trow + r) * 64] = f2bf(x2 * cs[r] + x1 * sn[r]);
                }
            }
        }
    } else {
        // V transposed: [512][T], rows = v-channel, cols = t
#pragma unroll
        for (int i = 0; i < 4; ++i)
#pragma unroll
            for (int j = 0; j < 4; ++j) {
                int n = n0 + wn + lr + j * 16;
                int m = mbase + i * 16;
                ushort4 o;
                o.x = f2bf(acc[i][j][0]); o.y = f2bf(acc[i][j][1]);
                o.z = f2bf(acc[i][j][2]); o.w = f2bf(acc[i][j][3]);
                *(ushort4*)&Vto[(size_t)n * T + m] = o;
            }
    }
}

// ---------------------------------------------------------------------------
// Plain MFMA GEMM for the output projection: C fp32 [M][N]
// ---------------------------------------------------------------------------
__global__ __launch_bounds__(256) void gemm_bt_f32(const ushort* __restrict__ A,
                                                   const ushort* __restrict__ B,
                                                   float* __restrict__ C,
                                                   int M, int N, int K) {
    __shared__ __align__(16) ushort As[128 * 32];
    __shared__ __align__(16) ushort Bs[128 * 32];
    const int tid = threadIdx.x;
    const int w = tid >> 6, l = tid & 63;
    const int m0 = blockIdx.x * 128, n0 = blockIdx.y * 128;
    const int wm = (w >> 1) * 64, wn = (w & 1) * 64;
    const int lr = l & 15;
    const int lk = (l >> 4) * 8;

    f32x4 zero = {0.f, 0.f, 0.f, 0.f};
    f32x4 acc[4][4];
#pragma unroll
    for (int i = 0; i < 4; ++i)
#pragma unroll
        for (int j = 0; j < 4; ++j) acc[i][j] = zero;

    const int si0 = w * 2, si1 = w * 2 + 1;
    const int srow0 = si0 * 16 + (l >> 2);
    const int srow1 = si1 * 16 + (l >> 2);
    const int scol = (l & 3) * 8;
    const ushort* Ag0 = A + (size_t)(m0 + srow0) * K + scol;
    const ushort* Ag1 = A + (size_t)(m0 + srow1) * K + scol;
    const ushort* Bg0 = B + (size_t)(n0 + srow0) * K + scol;
    const ushort* Bg1 = B + (size_t)(n0 + srow1) * K + scol;
    ushort* Al0 = &As[si0 * 512]; ushort* Al1 = &As[si1 * 512];
    ushort* Bl0 = &Bs[si0 * 512]; ushort* Bl1 = &Bs[si1 * 512];

    for (int k0 = 0; k0 < K; k0 += 32) {
        gld_lds16(Ag0 + k0, Al0);
        gld_lds16(Ag1 + k0, Al1);
        gld_lds16(Bg0 + k0, Bl0);
        gld_lds16(Bg1 + k0, Bl1);
        __syncthreads();
        short8 af[4], bf[4];
#pragma unroll
        for (int i = 0; i < 4; ++i) af[i] = *(const short8*)&As[(wm + i * 16 + lr) * 32 + lk];
#pragma unroll
        for (int j = 0; j < 4; ++j) bf[j] = *(const short8*)&Bs[(wn + j * 16 + lr) * 32 + lk];
#pragma unroll
        for (int i = 0; i < 4; ++i)
#pragma unroll
            for (int j = 0; j < 4; ++j)
                acc[i][j] = MFMA16(af[i], bf[j], acc[i][j]);
        __syncthreads();
    }

    const int mbase = m0 + wm + (l >> 4) * 4;
    const int nbase = n0 + wn + lr;
#pragma unroll
    for (int i = 0; i < 4; ++i)
#pragma unroll
        for (int j = 0; j < 4; ++j)
#pragma unroll
            for (int r = 0; r < 4; ++r)
                C[(size_t)(mbase + i * 16 + r) * N + (nbase + j * 16)] = acc[i][j][r];
}

// ---------------------------------------------------------------------------
// Flash attention, MFMA bf16, load-balanced: grid (16, 32); block handles
// q-tiles blockIdx.x and 31-blockIdx.x (33 k-tiles each). Ps padded to
// stride 72 ushorts (2-way banks = free, 16B-aligned readback).
// ---------------------------------------------------------------------------
__global__ __launch_bounds__(256) void attn_mfma(const ushort* __restrict__ Q,
                                                 const ushort* __restrict__ K,
                                                 const ushort* __restrict__ Vt,
                                                 ushort* __restrict__ ctx, int T) {
    __shared__ __align__(16) ushort Ks[64 * 64];
    __shared__ __align__(16) ushort Vs[64 * 64];
    __shared__ __align__(16) ushort Ps[4][16 * 72];
    const int tid = threadIdx.x, w = tid >> 6, l = tid & 63;
    const int h = blockIdx.y;
    const int hk = h >> 2;
    const int lr = l & 15;
    const int lk = (l >> 4) * 8;
    const int quad = l >> 4;
    const ushort* Kb = K + (size_t)hk * T * 64;
    const ushort* Vb = Vt + (size_t)hk * 64 * T;

    const int si0 = w * 2, si1 = w * 2 + 1;
    const int srow0 = si0 * 8 + (l >> 3);
    const int srow1 = si1 * 8 + (l >> 3);
    const int scol = (l & 7) * 8;
    ushort* Kl0 = &Ks[si0 * 512]; ushort* Kl1 = &Ks[si1 * 512];
    ushort* Vl0 = &Vs[si0 * 512]; ushort* Vl1 = &Vs[si1 * 512];

    f32x4 zero = {0.f, 0.f, 0.f, 0.f};

    for (int phase = 0; phase < 2; ++phase) {
        const int qt = phase == 0 ? blockIdx.x : (T / 64 - 1 - blockIdx.x);

        const ushort* qp = Q + ((size_t)h * T + (size_t)qt * 64 + w * 16 + lr) * 64 + lk;
        short8 qf0 = *(const short8*)qp;
        short8 qf1 = *(const short8*)(qp + 32);

        f32x4 oacc[4];
#pragma unroll
        for (int j = 0; j < 4; ++j) oacc[j] = zero;
        float lsum[4] = {0.f, 0.f, 0.f, 0.f};

        const int ntiles = qt + 1;
        const int qabs = qt * 64 + w * 16 + quad * 4;

        for (int kt = 0; kt < ntiles; ++kt) {
            const int k0 = kt * 64;
            gld_lds16(Kb + (size_t)(k0 + srow0) * 64 + scol, Kl0);
            gld_lds16(Kb + (size_t)(k0 + srow1) * 64 + scol, Kl1);
            gld_lds16(Vb + (size_t)srow0 * T + k0 + scol, Vl0);
            gld_lds16(Vb + (size_t)srow1 * T + k0 + scol, Vl1);
            __syncthreads();
            // S = Q @ K^T
            f32x4 s[4];
#pragma unroll
            for (int j = 0; j < 4; ++j) {
                short8 kf0 = *(const short8*)&Ks[(j * 16 + lr) * 64 + lk];
                short8 kf1 = *(const short8*)&Ks[(j * 16 + lr) * 64 + 32 + lk];
                f32x4 z = zero;
                z = MFMA16(qf0, kf0, z);
                z = MFMA16(qf1, kf1, z);
                s[j] = z;
            }
            // mask + exp -> Ps (C/D layout -> [qrow][key], padded stride 72)
#pragma unroll
            for (int j = 0; j < 4; ++j) {
                int key = k0 + j * 16 + lr;
#pragma unroll
                for (int r = 0; r < 4; ++r) {
                    float p = (key <= qabs + r) ? __expf(s[j][r] * 0.125f) : 0.f;
                    lsum[r] += p;
                    Ps[w][(quad * 4 + r) * 72 + j * 16 + lr] = f2bf(p);
                }
            }
            // O += P @ V
#pragma unroll
            for (int ss = 0; ss < 2; ++ss) {
                short8 pf = *(const short8*)&Ps[w][lr * 72 + ss * 32 + lk];
#pragma unroll
                for (int j = 0; j < 4; ++j) {
                    short8 vf = *(const short8*)&Vs[(j * 16 + lr) * 64 + ss * 32 + lk];
                    oacc[j] = MFMA16(pf, vf, oacc[j]);
                }
            }
            __syncthreads();
        }
#pragma unroll
        for (int r = 0; r < 4; ++r) {
            float v = lsum[r];
            v += __shfl_xor(v, 1); v += __shfl_xor(v, 2);
            v += __shfl_xor(v, 4); v += __shfl_xor(v, 8);
            lsum[r] = 1.f / v;
        }
#pragma unroll
        for (int j = 0; j < 4; ++j) {
            int col = h * 64 + j * 16 + lr;
#pragma unroll
            for (int r = 0; r < 4; ++r) {
                int row = qt * 64 + w * 16 + quad * 4 + r;
                ctx[(size_t)row * 2048 + col] = f2bf(oacc[j][r] * lsum[r]);
            }
        }
    }
}

// ---------------------------------------------------------------------------
extern "C" void kernel_launch(void* const* d_in, const int* in_sizes, int n_in,
                              void* d_out, int out_size, void* d_ws, size_t ws_size,
                              hipStream_t stream) {
    const float* x  = (const float*)d_in[0];
    const float* Wq = (const float*)d_in[1];
    const float* Wk = (const float*)d_in[2];
    const float* Wv = (const float*)d_in[3];
    const float* Wo = (const float*)d_in[4];
    const int* start_pos = (const int*)d_in[5];
    float* out = (float*)d_out;

    const int T = T_SEQ, D = D_MODEL;
    const int KV = N_KV * HEAD_DIM;  // 512

    char* w = (char*)d_ws;
    float* cosT = (float*)w;            w += (size_t)32 * T * 4;
    float* sinT = (float*)w;            w += (size_t)32 * T * 4;
    ushort* xbf  = (ushort*)w;          w += (size_t)T * D * 2;     // aliased: ctx
    ushort* wqbf = (ushort*)w;          w += (size_t)D * D * 2;
    ushort* wkbf = (ushort*)w;          w += (size_t)KV * D * 2;
    ushort* wvbf = (ushort*)w;          w += (size_t)KV * D * 2;
    ushort* wobf = (ushort*)w;          w += (size_t)D * D * 2;
    ushort* qbf  = (ushort*)w;          w += (size_t)N_HEADS * T * 64 * 2;
    ushort* kbf  = (ushort*)w;          w += (size_t)N_KV * T * 64 * 2;
    ushort* vtbf = (ushort*)w;          w += (size_t)N_KV * 64 * T * 2;
    ushort* ctxbf = xbf;  // x fully consumed by gemm_qkv before attn writes ctx

    rope_tables_kernel<<<dim3(T), dim3(32), 0, stream>>>(cosT, sinT, start_pos, T);

    cast_all_kernel<<<dim3(14336), dim3(256), 0, stream>>>(x, Wq, Wk, Wv, Wo,
                                                           xbf, wqbf, wkbf, wvbf, wobf);

    gemm_qkv<<<dim3(T / 128, (D + 2 * KV) / 128), dim3(256), 0, stream>>>(
        xbf, wqbf, wkbf, wvbf, qbf, kbf, vtbf, cosT, sinT, T, D);

    attn_mfma<<<dim3(T / 128, N_HEADS), dim3(256), 0, stream>>>(qbf, kbf, vtbf, ctxbf, T);

    gemm_bt_f32<<<dim3(T / 128, D / 128), dim3(256), 0, stream>>>(ctxbf, wobf, out, T, D, D);
}